// Round 2
// baseline (1745.382 us; speedup 1.0000x reference)
//
#include <hip/hip_runtime.h>
#include <hip/hip_bf16.h>

#define NN 100000
#define NE 1000000

// ---------------- degree ----------------
__global__ __launch_bounds__(256) void deg_kernel(const int* __restrict__ dst, float* __restrict__ deg) {
    int e = blockIdx.x * 256 + threadIdx.x;
    if (e < NE) atomicAdd(&deg[dst[e]], 1.0f);
}

// ---------------- row GEMM: out[n,64] = in[n,:K] @ W[K,64] ----------------
template <int K>
__global__ __launch_bounds__(256) void rowgemm_kernel(const float* __restrict__ in,
                                                      const float* __restrict__ W,
                                                      float* __restrict__ out) {
    __shared__ float wsh[K * 64];
    int tid = threadIdx.x;
    for (int i = tid; i < K * 64; i += 256) wsh[i] = W[i];
    __syncthreads();
    int node = blockIdx.x * 4 + (tid >> 6);
    int lane = tid & 63;
    if (node >= NN) return;
    const float* row = in + (size_t)node * K;
    float acc = 0.f;
#pragma unroll 8
    for (int k = 0; k < K; ++k) acc += row[k] * wsh[k * 64 + lane];
    out[(size_t)node * 64 + lane] = acc;
}

// ---------------- scatter: agg[dst] += v[src], 64 feats, wave per edge ----------------
__global__ __launch_bounds__(256) void scatter_kernel(const float* __restrict__ v,
                                                      const int* __restrict__ src,
                                                      const int* __restrict__ dst,
                                                      float* __restrict__ agg) {
    int idx = blockIdx.x * 256 + threadIdx.x;
    int e = idx >> 6;
    int lane = idx & 63;
    if (e < NE) {
        int s = src[e];
        int d = dst[e];
        atomicAdd(&agg[(size_t)d * 64 + lane], v[(size_t)s * 64 + lane]);
    }
}

// ---------------- fused mean + bl + x@Wr + LayerNorm + ReLU ----------------
template <int K>
__global__ __launch_bounds__(256) void ln_kernel(const float* __restrict__ agg,
                                                 const float* __restrict__ deg,
                                                 const float* __restrict__ bl,
                                                 const float* __restrict__ xin,
                                                 const float* __restrict__ Wr,
                                                 const float* __restrict__ g,
                                                 const float* __restrict__ be,
                                                 float* __restrict__ out) {
    __shared__ float wsh[K * 64];
    __shared__ float bls[64], gs[64], bes[64];
    int tid = threadIdx.x;
    for (int i = tid; i < K * 64; i += 256) wsh[i] = Wr[i];
    if (tid < 64) { bls[tid] = bl[tid]; gs[tid] = g[tid]; bes[tid] = be[tid]; }
    __syncthreads();
    int node = blockIdx.x * 4 + (tid >> 6);
    int lane = tid & 63;
    if (node >= NN) return;
    const float* row = xin + (size_t)node * K;
    float acc = 0.f;
#pragma unroll 8
    for (int k = 0; k < K; ++k) acc += row[k] * wsh[k * 64 + lane];
    float dg = deg[node];
    dg = dg < 1.f ? 1.f : dg;
    float v = agg[(size_t)node * 64 + lane] / dg + bls[lane] + acc;
    // LayerNorm across the 64 lanes (one row)
    float s = v, s2 = v * v;
#pragma unroll
    for (int o = 32; o > 0; o >>= 1) {
        s += __shfl_xor(s, o, 64);
        s2 += __shfl_xor(s2, o, 64);
    }
    float mu = s * (1.f / 64.f);
    float var = s2 * (1.f / 64.f) - mu * mu;
    float r = rsqrtf(var + 1e-5f);
    float hv = (v - mu) * r * gs[lane] + bes[lane];
    out[(size_t)node * 64 + lane] = hv > 0.f ? hv : 0.f;
}

// ---------------- edge MLP: [h[src] | h[dst] | ea] -> 64 -> 32 -> 1 ----------------
__global__ __launch_bounds__(256) void edge_mlp_kernel(const float* __restrict__ h,
                                                       const int* __restrict__ src,
                                                       const int* __restrict__ dst,
                                                       const float* __restrict__ ea,
                                                       const float* __restrict__ W1,
                                                       const float* __restrict__ b1,
                                                       const float* __restrict__ W2,
                                                       const float* __restrict__ b2,
                                                       const float* __restrict__ W3,
                                                       const float* __restrict__ b3,
                                                       float* __restrict__ out) {
    __shared__ float w1s[144 * 64];   // 36.9 KB
    __shared__ float w2s[64 * 32];    // 8 KB
    __shared__ float w3s[32];
    __shared__ float b1s[64], b2s[32];
    __shared__ float b3s;
    int tid = threadIdx.x;
    for (int i = tid; i < 144 * 64; i += 256) w1s[i] = W1[i];
    for (int i = tid; i < 64 * 32; i += 256) w2s[i] = W2[i];
    if (tid < 32) w3s[tid] = W3[tid];
    if (tid < 64) b1s[tid] = b1[tid];
    if (tid < 32) b2s[tid] = b2[tid];
    if (tid == 0) b3s = b3[0];
    __syncthreads();

    int e = blockIdx.x * 256 + tid;
    if (e >= NE) return;
    int s = src[e];
    int d = dst[e];

    float z1[64];
#pragma unroll
    for (int j = 0; j < 64; ++j) z1[j] = b1s[j];

    auto acc_row = [&](float vk, const float* wrow) {
#pragma unroll
        for (int j = 0; j < 64; j += 4) {
            float4 w = *(const float4*)(wrow + j);
            z1[j]     += vk * w.x;
            z1[j + 1] += vk * w.y;
            z1[j + 2] += vk * w.z;
            z1[j + 3] += vk * w.w;
        }
    };

    const float* hs = h + (size_t)s * 64;
#pragma unroll 2
    for (int k = 0; k < 64; k += 4) {
        float4 hv = *(const float4*)(hs + k);
        acc_row(hv.x, &w1s[(k) * 64]);
        acc_row(hv.y, &w1s[(k + 1) * 64]);
        acc_row(hv.z, &w1s[(k + 2) * 64]);
        acc_row(hv.w, &w1s[(k + 3) * 64]);
    }
    const float* hd = h + (size_t)d * 64;
#pragma unroll 2
    for (int k = 0; k < 64; k += 4) {
        float4 hv = *(const float4*)(hd + k);
        acc_row(hv.x, &w1s[(64 + k) * 64]);
        acc_row(hv.y, &w1s[(64 + k + 1) * 64]);
        acc_row(hv.z, &w1s[(64 + k + 2) * 64]);
        acc_row(hv.w, &w1s[(64 + k + 3) * 64]);
    }
    const float* er = ea + (size_t)e * 16;
#pragma unroll
    for (int k = 0; k < 16; k += 4) {
        float4 av = *(const float4*)(er + k);
        acc_row(av.x, &w1s[(128 + k) * 64]);
        acc_row(av.y, &w1s[(128 + k + 1) * 64]);
        acc_row(av.z, &w1s[(128 + k + 2) * 64]);
        acc_row(av.w, &w1s[(128 + k + 3) * 64]);
    }
#pragma unroll
    for (int j = 0; j < 64; ++j) z1[j] = z1[j] > 0.f ? z1[j] : 0.f;

    float z2[32];
#pragma unroll
    for (int j = 0; j < 32; ++j) z2[j] = b2s[j];
#pragma unroll
    for (int k = 0; k < 64; ++k) {
        float vk = z1[k];
#pragma unroll
        for (int j = 0; j < 32; j += 4) {
            float4 w = *(const float4*)&w2s[k * 32 + j];
            z2[j]     += vk * w.x;
            z2[j + 1] += vk * w.y;
            z2[j + 2] += vk * w.z;
            z2[j + 3] += vk * w.w;
        }
    }
    float o = b3s;
#pragma unroll
    for (int j = 0; j < 32; ++j) {
        float v2 = z2[j] > 0.f ? z2[j] : 0.f;
        o += v2 * w3s[j];
    }
    out[e] = o;
}

extern "C" void kernel_launch(void* const* d_in, const int* in_sizes, int n_in,
                              void* d_out, int out_size, void* d_ws, size_t ws_size,
                              hipStream_t stream) {
    const float* x   = (const float*)d_in[0];
    const int*   ei  = (const int*)d_in[1];
    const float* ea  = (const float*)d_in[2];
    const float* Wl0 = (const float*)d_in[3];
    const float* bl0 = (const float*)d_in[4];
    const float* Wr0 = (const float*)d_in[5];
    const float* g0  = (const float*)d_in[6];
    const float* be0 = (const float*)d_in[7];
    const float* Wl1 = (const float*)d_in[8];
    const float* bl1 = (const float*)d_in[9];
    const float* Wr1 = (const float*)d_in[10];
    const float* g1  = (const float*)d_in[11];
    const float* be1 = (const float*)d_in[12];
    const float* W1  = (const float*)d_in[13];
    const float* b1  = (const float*)d_in[14];
    const float* W2  = (const float*)d_in[15];
    const float* b2  = (const float*)d_in[16];
    const float* W3  = (const float*)d_in[17];
    const float* b3  = (const float*)d_in[18];
    float* out = (float*)d_out;

    const int* src = ei;
    const int* dstp = ei + NE;

    char* ws = (char*)d_ws;
    float* agg  = (float*)(ws);              // 25,600,000 B
    float* deg  = (float*)(ws + 25600000);   //    400,000 B
    float* bufW = (float*)(ws + 26000000);   // 25,600,000 B
    float* bufH = (float*)(ws + 51600000);   // 25,600,000 B

    // zero agg + deg (contiguous 26 MB)
    hipMemsetAsync(agg, 0, 26000000, stream);

    deg_kernel<<<(NE + 255) / 256, 256, 0, stream>>>(dstp, deg);

    // ---- layer 0 ----
    rowgemm_kernel<128><<<(NN + 3) / 4, 256, 0, stream>>>(x, Wl0, bufW);
    scatter_kernel<<<NE / 4, 256, 0, stream>>>(bufW, src, dstp, agg);
    ln_kernel<128><<<(NN + 3) / 4, 256, 0, stream>>>(agg, deg, bl0, x, Wr0, g0, be0, bufH);

    // ---- layer 1 ----
    hipMemsetAsync(agg, 0, 25600000, stream);
    rowgemm_kernel<64><<<(NN + 3) / 4, 256, 0, stream>>>(bufH, Wl1, bufW);
    scatter_kernel<<<NE / 4, 256, 0, stream>>>(bufW, src, dstp, agg);
    ln_kernel<64><<<(NN + 3) / 4, 256, 0, stream>>>(agg, deg, bl1, bufH, Wr1, g1, be1, bufH);

    // ---- edge MLP ----
    edge_mlp_kernel<<<(NE + 255) / 256, 256, 0, stream>>>(bufH, src, dstp, ea,
                                                          W1, b1, W2, b2, W3, b3, out);
}

// Round 4
// 971.936 us; speedup vs baseline: 1.7958x; 1.7958x over previous
//
#include <hip/hip_runtime.h>
#include <hip/hip_bf16.h>

#define NN 100000
#define NE 1000000

typedef _Float16 half8  __attribute__((ext_vector_type(8)));
typedef float    f32x4  __attribute__((ext_vector_type(4)));

__device__ inline unsigned int pk2(float a, float b) {
    auto h = __builtin_amdgcn_cvt_pkrtz(a, b);   // __fp16 ext_vector(2)
    return __builtin_bit_cast(unsigned int, h);
}

// ---------------- int degree histogram ----------------
__global__ __launch_bounds__(256) void deg_int_kernel(const int* __restrict__ dst, int* __restrict__ degi) {
    int e = blockIdx.x * 256 + threadIdx.x;
    if (e < NE) atomicAdd(&degi[dst[e]], 1);
}

// ---------------- scan A: per-512-block partial sums ----------------
__global__ __launch_bounds__(256) void scan_partial(const int* __restrict__ degi, int* __restrict__ bs) {
    __shared__ int sd[256];
    int b = blockIdx.x, t = threadIdx.x;
    int i = b * 512 + t;
    int v = (i < NN ? degi[i] : 0) + (i + 256 < NN ? degi[i + 256] : 0);
    sd[t] = v;
    __syncthreads();
    for (int o = 128; o > 0; o >>= 1) {
        if (t < o) sd[t] += sd[t + o];
        __syncthreads();
    }
    if (t == 0) bs[b] = sd[0];
}

// ---------------- scan B: spine exclusive scan (196 elems) ----------------
__global__ __launch_bounds__(256) void scan_spine(const int* __restrict__ bs, int* __restrict__ bo) {
    __shared__ int sd[256];
    int t = threadIdx.x;
    int v = (t < 196) ? bs[t] : 0;
    sd[t] = v;
    __syncthreads();
    for (int o = 1; o < 256; o <<= 1) {
        int add = (t >= o) ? sd[t - o] : 0;
        __syncthreads();
        sd[t] += add;
        __syncthreads();
    }
    if (t < 196) bo[t] = sd[t] - v;   // exclusive
}

// ---------------- scan C: final offsets + cursor copy ----------------
__global__ __launch_bounds__(512) void scan_final(const int* __restrict__ degi, const int* __restrict__ bo,
                                                  int* __restrict__ offs, int* __restrict__ cursor) {
    __shared__ int sd[512];
    int b = blockIdx.x, t = threadIdx.x;
    int i = b * 512 + t;
    int v = (i < NN) ? degi[i] : 0;
    sd[t] = v;
    __syncthreads();
    for (int o = 1; o < 512; o <<= 1) {
        int add = (t >= o) ? sd[t - o] : 0;
        __syncthreads();
        sd[t] += add;
        __syncthreads();
    }
    if (i < NN) {
        int ex = bo[b] + sd[t] - v;
        offs[i] = ex;
        cursor[i] = ex;
    }
}

// ---------------- CSR fill: csr_src sorted by dst ----------------
__global__ __launch_bounds__(256) void csr_fill(const int* __restrict__ src, const int* __restrict__ dst,
                                                int* __restrict__ cursor, int* __restrict__ csr) {
    int e = blockIdx.x * 256 + threadIdx.x;
    if (e < NE) {
        int pos = atomicAdd(&cursor[dst[e]], 1);
        csr[pos] = src[e];
    }
}

// ---------------- gather-reduce: agg[n] = sum over CSR neighbors of v[src] ----------------
__global__ __launch_bounds__(256) void gather_reduce(const float* __restrict__ v, const int* __restrict__ csr,
                                                     const int* __restrict__ offs, const int* __restrict__ degi,
                                                     float* __restrict__ agg) {
    int tid = threadIdx.x;
    int node = blockIdx.x * 4 + (tid >> 6);
    int lane = tid & 63;
    if (node >= NN) return;
    int off = offs[node], cnt = degi[node];
    float acc = 0.f;
    int j = 0;
    for (; j + 4 <= cnt; j += 4) {
        int r0 = csr[off + j], r1 = csr[off + j + 1], r2 = csr[off + j + 2], r3 = csr[off + j + 3];
        float a0 = v[(size_t)r0 * 64 + lane];
        float a1 = v[(size_t)r1 * 64 + lane];
        float a2 = v[(size_t)r2 * 64 + lane];
        float a3 = v[(size_t)r3 * 64 + lane];
        acc += a0; acc += a1; acc += a2; acc += a3;
    }
    for (; j < cnt; ++j) acc += v[(size_t)csr[off + j] * 64 + lane];
    agg[(size_t)node * 64 + lane] = acc;
}

// ---------------- old atomic scatter (fallback if ws too small) ----------------
__global__ __launch_bounds__(256) void scatter_kernel(const float* __restrict__ v,
                                                      const int* __restrict__ src,
                                                      const int* __restrict__ dst,
                                                      float* __restrict__ agg) {
    int idx = blockIdx.x * 256 + threadIdx.x;
    int e = idx >> 6;
    int lane = idx & 63;
    if (e < NE) {
        int s = src[e];
        int d = dst[e];
        atomicAdd(&agg[(size_t)d * 64 + lane], v[(size_t)s * 64 + lane]);
    }
}

// ---------------- row GEMM: out[n,64] = in[n,:K] @ W[K,64] ----------------
template <int K>
__global__ __launch_bounds__(256) void rowgemm_kernel(const float* __restrict__ in,
                                                      const float* __restrict__ W,
                                                      float* __restrict__ out) {
    __shared__ float wsh[K * 64];
    int tid = threadIdx.x;
    for (int i = tid; i < K * 64; i += 256) wsh[i] = W[i];
    __syncthreads();
    int node = blockIdx.x * 4 + (tid >> 6);
    int lane = tid & 63;
    if (node >= NN) return;
    const float* row = in + (size_t)node * K;
    float acc = 0.f;
#pragma unroll 8
    for (int k = 0; k < K; ++k) acc += row[k] * wsh[k * 64 + lane];
    out[(size_t)node * 64 + lane] = acc;
}

// ---------------- fused mean + bl + x@Wr + LayerNorm + ReLU (int deg) ----------------
template <int K>
__global__ __launch_bounds__(256) void ln_kernel(const float* __restrict__ agg,
                                                 const int* __restrict__ degi,
                                                 const float* __restrict__ bl,
                                                 const float* __restrict__ xin,
                                                 const float* __restrict__ Wr,
                                                 const float* __restrict__ g,
                                                 const float* __restrict__ be,
                                                 float* __restrict__ out) {
    __shared__ float wsh[K * 64];
    __shared__ float bls[64], gs[64], bes[64];
    int tid = threadIdx.x;
    for (int i = tid; i < K * 64; i += 256) wsh[i] = Wr[i];
    if (tid < 64) { bls[tid] = bl[tid]; gs[tid] = g[tid]; bes[tid] = be[tid]; }
    __syncthreads();
    int node = blockIdx.x * 4 + (tid >> 6);
    int lane = tid & 63;
    if (node >= NN) return;
    const float* row = xin + (size_t)node * K;
    float acc = 0.f;
#pragma unroll 8
    for (int k = 0; k < K; ++k) acc += row[k] * wsh[k * 64 + lane];
    float dg = (float)degi[node];
    dg = dg < 1.f ? 1.f : dg;
    float v = agg[(size_t)node * 64 + lane] / dg + bls[lane] + acc;
    float s = v, s2 = v * v;
#pragma unroll
    for (int o = 32; o > 0; o >>= 1) {
        s += __shfl_xor(s, o, 64);
        s2 += __shfl_xor(s2, o, 64);
    }
    float mu = s * (1.f / 64.f);
    float var = s2 * (1.f / 64.f) - mu * mu;
    float r = rsqrtf(var + 1e-5f);
    float hv = (v - mu) * r * gs[lane] + bes[lane];
    out[(size_t)node * 64 + lane] = hv > 0.f ? hv : 0.f;
}

// ---------------- edge MLP via f16 MFMA ----------------
// Per block (4 waves): stage W1^T [64][160] f16 (zero-padded K 144..159) + W2^T [32][64] f16.
// Per wave per tile: 16 edges. A-tile [16][160] f16 in LDS, 5 K-steps x 4 N-tiles MFMA,
// z1 (relu, f16) through LDS [16][72], 2x2 MFMA for layer 2, shfl-reduce + W3 dot for out.
#define NTILES 15625   // 1M / 64 edges per block-tile
__global__ __launch_bounds__(256) void edge_mlp_mfma(const float* __restrict__ h,
                                                     const int* __restrict__ src,
                                                     const int* __restrict__ dst,
                                                     const float* __restrict__ ea,
                                                     const float* __restrict__ W1,
                                                     const float* __restrict__ b1,
                                                     const float* __restrict__ W2,
                                                     const float* __restrict__ b2,
                                                     const float* __restrict__ W3,
                                                     const float* __restrict__ b3,
                                                     float* __restrict__ out) {
    __shared__ __align__(16) _Float16 w1t[64 * 160];   // [n][k], 20480 B
    __shared__ __align__(16) _Float16 w2t[32 * 64];    // [n][k],  4096 B
    __shared__ __align__(16) _Float16 atile[4][16 * 160]; // per-wave, 20480 B
    __shared__ __align__(16) _Float16 z1t[4][16 * 72];    // per-wave,  9216 B

    int tid = threadIdx.x;
    // zero W1^T (for K-pad 144..159), then transpose-stage weights as f16
    for (int i = tid; i < 64 * 160 / 2; i += 256) ((unsigned int*)w1t)[i] = 0u;
    __syncthreads();
    for (int i = tid; i < 144 * 64; i += 256) {
        int k = i >> 6, n = i & 63;
        w1t[n * 160 + k] = (_Float16)W1[i];
    }
    for (int i = tid; i < 64 * 32; i += 256) {
        int k = i >> 5, n = i & 31;
        w2t[n * 64 + k] = (_Float16)W2[i];
    }
    __syncthreads();

    int wave = tid >> 6;
    int lane = tid & 63;
    int g = lane >> 4;    // 0..3 : k-chunk group / C row group
    int r = lane & 15;    // 0..15: A row (edge) / B col (channel) / C col

    // preload B fragments into registers (shared by all tiles)
    half8 b1f[4][5];
#pragma unroll
    for (int nt = 0; nt < 4; ++nt)
#pragma unroll
        for (int ks = 0; ks < 5; ++ks)
            b1f[nt][ks] = *(const half8*)&w1t[(nt * 16 + r) * 160 + ks * 32 + g * 8];
    half8 b2f[2][2];
#pragma unroll
    for (int nt = 0; nt < 2; ++nt)
#pragma unroll
        for (int ks = 0; ks < 2; ++ks)
            b2f[nt][ks] = *(const half8*)&w2t[(nt * 16 + r) * 64 + ks * 32 + g * 8];

    float b1c0 = b1[0 * 16 + r], b1c1 = b1[1 * 16 + r], b1c2 = b1[2 * 16 + r], b1c3 = b1[3 * 16 + r];
    float b2c0 = b2[0 * 16 + r], b2c1 = b2[1 * 16 + r];
    float w3c0 = W3[0 * 16 + r], w3c1 = W3[1 * 16 + r];
    float b3v = b3[0];

    _Float16* A = &atile[wave][0];
    _Float16* Z = &z1t[wave][0];
    int eq = lane >> 2;   // edge-in-tile 0..15 (staging role)
    int qq = lane & 3;    // quarter 0..3     (staging role)

    for (int t = blockIdx.x; t < NTILES; t += gridDim.x) {
        int ebase = t * 64 + wave * 16;
        int e = ebase + eq;
        int s = src[e];
        int d = dst[e];

        // ---- stage A: [h_s(64) | h_d(64) | ea(16) | 0(16)] as f16 ----
        const float* srcrow = (qq < 2) ? (h + (size_t)s * 64 + qq * 32)
                                       : (h + (size_t)d * 64 + (qq - 2) * 32);
        unsigned int pk[16];
#pragma unroll
        for (int i = 0; i < 8; ++i) {
            float4 v = ((const float4*)srcrow)[i];
            pk[2 * i]     = pk2(v.x, v.y);
            pk[2 * i + 1] = pk2(v.z, v.w);
        }
        unsigned int* dsta = (unsigned int*)(A + eq * 160 + qq * 32);
#pragma unroll
        for (int i = 0; i < 4; ++i)
            ((uint4*)dsta)[i] = make_uint4(pk[4 * i], pk[4 * i + 1], pk[4 * i + 2], pk[4 * i + 3]);
        float4 av = *(const float4*)(ea + (size_t)e * 16 + qq * 4);
        uint2 eapk; eapk.x = pk2(av.x, av.y); eapk.y = pk2(av.z, av.w);
        *(uint2*)(A + eq * 160 + 128 + qq * 4) = eapk;
        uint2 zz; zz.x = 0u; zz.y = 0u;
        *(uint2*)(A + eq * 160 + 144 + qq * 4) = zz;   // zero pad K 144..159

        // ---- layer 1: C[16e x 64] = A @ W1 + b1 ----
        f32x4 c1_0 = {b1c0, b1c0, b1c0, b1c0};
        f32x4 c1_1 = {b1c1, b1c1, b1c1, b1c1};
        f32x4 c1_2 = {b1c2, b1c2, b1c2, b1c2};
        f32x4 c1_3 = {b1c3, b1c3, b1c3, b1c3};
#pragma unroll
        for (int ks = 0; ks < 5; ++ks) {
            half8 af = *(const half8*)(A + r * 160 + ks * 32 + g * 8);
            c1_0 = __builtin_amdgcn_mfma_f32_16x16x32_f16(af, b1f[0][ks], c1_0, 0, 0, 0);
            c1_1 = __builtin_amdgcn_mfma_f32_16x16x32_f16(af, b1f[1][ks], c1_1, 0, 0, 0);
            c1_2 = __builtin_amdgcn_mfma_f32_16x16x32_f16(af, b1f[2][ks], c1_2, 0, 0, 0);
            c1_3 = __builtin_amdgcn_mfma_f32_16x16x32_f16(af, b1f[3][ks], c1_3, 0, 0, 0);
        }
        // relu -> f16 -> z1 LDS tile [16][72]
#pragma unroll
        for (int rr = 0; rr < 4; ++rr) {
            float v0 = c1_0[rr]; v0 = v0 > 0.f ? v0 : 0.f;
            float v1 = c1_1[rr]; v1 = v1 > 0.f ? v1 : 0.f;
            float v2 = c1_2[rr]; v2 = v2 > 0.f ? v2 : 0.f;
            float v3 = c1_3[rr]; v3 = v3 > 0.f ? v3 : 0.f;
            int row = g * 4 + rr;
            Z[row * 72 + 0 * 16 + r] = (_Float16)v0;
            Z[row * 72 + 1 * 16 + r] = (_Float16)v1;
            Z[row * 72 + 2 * 16 + r] = (_Float16)v2;
            Z[row * 72 + 3 * 16 + r] = (_Float16)v3;
        }

        // ---- layer 2: C2[16e x 32] = z1 @ W2 + b2 ----
        f32x4 c2_0 = {b2c0, b2c0, b2c0, b2c0};
        f32x4 c2_1 = {b2c1, b2c1, b2c1, b2c1};
#pragma unroll
        for (int ks = 0; ks < 2; ++ks) {
            half8 a2 = *(const half8*)(Z + r * 72 + ks * 32 + g * 8);
            c2_0 = __builtin_amdgcn_mfma_f32_16x16x32_f16(a2, b2f[0][ks], c2_0, 0, 0, 0);
            c2_1 = __builtin_amdgcn_mfma_f32_16x16x32_f16(a2, b2f[1][ks], c2_1, 0, 0, 0);
        }

        // ---- layer 3: relu(z2) . w3, reduce over 32 channels ----
        float t0, t1, t2, t3;
        {
            float u0, u1;
            u0 = c2_0[0]; u0 = u0 > 0.f ? u0 : 0.f;
            u1 = c2_1[0]; u1 = u1 > 0.f ? u1 : 0.f;
            t0 = u0 * w3c0 + u1 * w3c1;
            u0 = c2_0[1]; u0 = u0 > 0.f ? u0 : 0.f;
            u1 = c2_1[1]; u1 = u1 > 0.f ? u1 : 0.f;
            t1 = u0 * w3c0 + u1 * w3c1;
            u0 = c2_0[2]; u0 = u0 > 0.f ? u0 : 0.f;
            u1 = c2_1[2]; u1 = u1 > 0.f ? u1 : 0.f;
            t2 = u0 * w3c0 + u1 * w3c1;
            u0 = c2_0[3]; u0 = u0 > 0.f ? u0 : 0.f;
            u1 = c2_1[3]; u1 = u1 > 0.f ? u1 : 0.f;
            t3 = u0 * w3c0 + u1 * w3c1;
        }
#pragma unroll
        for (int m = 1; m < 16; m <<= 1) {
            t0 += __shfl_xor(t0, m, 64);
            t1 += __shfl_xor(t1, m, 64);
            t2 += __shfl_xor(t2, m, 64);
            t3 += __shfl_xor(t3, m, 64);
        }
        // rows g*4 + {0..3}; lane r==rr writes t_rr
        if (r == 0) out[ebase + g * 4 + 0] = t0 + b3v;
        if (r == 1) out[ebase + g * 4 + 1] = t1 + b3v;
        if (r == 2) out[ebase + g * 4 + 2] = t2 + b3v;
        if (r == 3) out[ebase + g * 4 + 3] = t3 + b3v;
    }
}

// ---------------- workspace layout (bytes) ----------------
#define WS_AGG  0
#define WS_BUFW 25600000
#define WS_BUFH 51200000
#define WS_DEGI 76800000
#define WS_OFFS 77200000
#define WS_CSR  77600000
#define WS_NEED 81600000

extern "C" void kernel_launch(void* const* d_in, const int* in_sizes, int n_in,
                              void* d_out, int out_size, void* d_ws, size_t ws_size,
                              hipStream_t stream) {
    const float* x   = (const float*)d_in[0];
    const int*   ei  = (const int*)d_in[1];
    const float* ea  = (const float*)d_in[2];
    const float* Wl0 = (const float*)d_in[3];
    const float* bl0 = (const float*)d_in[4];
    const float* Wr0 = (const float*)d_in[5];
    const float* g0  = (const float*)d_in[6];
    const float* be0 = (const float*)d_in[7];
    const float* Wl1 = (const float*)d_in[8];
    const float* bl1 = (const float*)d_in[9];
    const float* Wr1 = (const float*)d_in[10];
    const float* g1  = (const float*)d_in[11];
    const float* be1 = (const float*)d_in[12];
    const float* W1  = (const float*)d_in[13];
    const float* b1  = (const float*)d_in[14];
    const float* W2  = (const float*)d_in[15];
    const float* b2  = (const float*)d_in[16];
    const float* W3  = (const float*)d_in[17];
    const float* b3  = (const float*)d_in[18];
    float* out = (float*)d_out;

    const int* src  = ei;
    const int* dstp = ei + NE;

    char* ws = (char*)d_ws;
    float* agg  = (float*)(ws + WS_AGG);
    float* bufW = (float*)(ws + WS_BUFW);
    float* bufH = (float*)(ws + WS_BUFH);
    int*   degi = (int*)(ws + WS_DEGI);

    hipMemsetAsync(degi, 0, 400000, stream);
    deg_int_kernel<<<(NE + 255) / 256, 256, 0, stream>>>(dstp, degi);

    bool csr_ok = ws_size >= (size_t)WS_NEED;
    if (csr_ok) {
        int* offs   = (int*)(ws + WS_OFFS);
        int* csr    = (int*)(ws + WS_CSR);
        int* cursor = (int*)(ws + WS_AGG);          // aliases agg (dead until gather0)
        int* bsum   = (int*)(ws + WS_BUFW);         // aliases bufW (dead until rowgemm0)
        int* boff   = (int*)(ws + WS_BUFW + 4096);

        scan_partial<<<196, 256, 0, stream>>>(degi, bsum);
        scan_spine<<<1, 256, 0, stream>>>(bsum, boff);
        scan_final<<<196, 512, 0, stream>>>(degi, boff, offs, cursor);
        csr_fill<<<(NE + 255) / 256, 256, 0, stream>>>(src, dstp, cursor, csr);

        // ---- layer 0 ----
        rowgemm_kernel<128><<<NN / 4, 256, 0, stream>>>(x, Wl0, bufW);
        gather_reduce<<<NN / 4, 256, 0, stream>>>(bufW, csr, offs, degi, agg);
        ln_kernel<128><<<NN / 4, 256, 0, stream>>>(agg, degi, bl0, x, Wr0, g0, be0, bufH);

        // ---- layer 1 ----
        rowgemm_kernel<64><<<NN / 4, 256, 0, stream>>>(bufH, Wl1, bufW);
        gather_reduce<<<NN / 4, 256, 0, stream>>>(bufW, csr, offs, degi, agg);
        ln_kernel<64><<<NN / 4, 256, 0, stream>>>(agg, degi, bl1, bufH, Wr1, g1, be1, bufH);
    } else {
        // fallback: atomic scatter path
        hipMemsetAsync(agg, 0, 25600000, stream);
        rowgemm_kernel<128><<<NN / 4, 256, 0, stream>>>(x, Wl0, bufW);
        scatter_kernel<<<NE / 4, 256, 0, stream>>>(bufW, src, dstp, agg);
        ln_kernel<128><<<NN / 4, 256, 0, stream>>>(agg, degi, bl0, x, Wr0, g0, be0, bufH);

        hipMemsetAsync(agg, 0, 25600000, stream);
        rowgemm_kernel<64><<<NN / 4, 256, 0, stream>>>(bufH, Wl1, bufW);
        scatter_kernel<<<NE / 4, 256, 0, stream>>>(bufW, src, dstp, agg);
        ln_kernel<64><<<NN / 4, 256, 0, stream>>>(agg, degi, bl1, bufH, Wr1, g1, be1, bufH);
    }

    // ---- edge MLP (f16 MFMA) ----
    edge_mlp_mfma<<<3125, 256, 0, stream>>>(bufH, src, dstp, ea,
                                            W1, b1, W2, b2, W3, b3, out);
}

// Round 6
// 588.961 us; speedup vs baseline: 2.9635x; 1.6503x over previous
//
#include <hip/hip_runtime.h>
#include <hip/hip_bf16.h>

#define NN 100000
#define NE 1000000

typedef _Float16 half8  __attribute__((ext_vector_type(8)));
typedef float    f32x4  __attribute__((ext_vector_type(4)));

__device__ inline unsigned int pk2(float a, float b) {
    auto h = __builtin_amdgcn_cvt_pkrtz(a, b);   // __fp16 ext_vector(2)
    return __builtin_bit_cast(unsigned int, h);
}
__device__ inline float f16lo(unsigned int u) {
    return (float)__builtin_bit_cast(_Float16, (unsigned short)(u & 0xffffu));
}
__device__ inline float f16hi(unsigned int u) {
    return (float)__builtin_bit_cast(_Float16, (unsigned short)(u >> 16));
}

// ---------------- int degree histogram ----------------
__global__ __launch_bounds__(256) void deg_int_kernel(const int* __restrict__ dst, int* __restrict__ degi) {
    int e = blockIdx.x * 256 + threadIdx.x;
    if (e < NE) atomicAdd(&degi[dst[e]], 1);
}

// ---------------- scan A: per-512-block partial sums ----------------
__global__ __launch_bounds__(256) void scan_partial(const int* __restrict__ degi, int* __restrict__ bs) {
    __shared__ int sd[256];
    int b = blockIdx.x, t = threadIdx.x;
    int i = b * 512 + t;
    int v = (i < NN ? degi[i] : 0) + (i + 256 < NN ? degi[i + 256] : 0);
    sd[t] = v;
    __syncthreads();
    for (int o = 128; o > 0; o >>= 1) {
        if (t < o) sd[t] += sd[t + o];
        __syncthreads();
    }
    if (t == 0) bs[b] = sd[0];
}

// ---------------- scan B: spine exclusive scan (196 elems) ----------------
__global__ __launch_bounds__(256) void scan_spine(const int* __restrict__ bs, int* __restrict__ bo) {
    __shared__ int sd[256];
    int t = threadIdx.x;
    int v = (t < 196) ? bs[t] : 0;
    sd[t] = v;
    __syncthreads();
    for (int o = 1; o < 256; o <<= 1) {
        int add = (t >= o) ? sd[t - o] : 0;
        __syncthreads();
        sd[t] += add;
        __syncthreads();
    }
    if (t < 196) bo[t] = sd[t] - v;   // exclusive
}

// ---------------- scan C: final offsets + cursor copy ----------------
__global__ __launch_bounds__(512) void scan_final(const int* __restrict__ degi, const int* __restrict__ bo,
                                                  int* __restrict__ offs, int* __restrict__ cursor) {
    __shared__ int sd[512];
    int b = blockIdx.x, t = threadIdx.x;
    int i = b * 512 + t;
    int v = (i < NN) ? degi[i] : 0;
    sd[t] = v;
    __syncthreads();
    for (int o = 1; o < 512; o <<= 1) {
        int add = (t >= o) ? sd[t - o] : 0;
        __syncthreads();
        sd[t] += add;
        __syncthreads();
    }
    if (i < NN) {
        int ex = bo[b] + sd[t] - v;
        offs[i] = ex;
        cursor[i] = ex;
    }
}

// ---------------- CSR fill: csr_src sorted by dst ----------------
__global__ __launch_bounds__(256) void csr_fill(const int* __restrict__ src, const int* __restrict__ dst,
                                                int* __restrict__ cursor, int* __restrict__ csr) {
    int e = blockIdx.x * 256 + threadIdx.x;
    if (e < NE) {
        int pos = atomicAdd(&cursor[dst[e]], 1);
        csr[pos] = src[e];
    }
}

// ---------------- node GEMM: bufP[n, 0:128] = in[n,:K] @ [WL | WR]  (f16 out) ----------------
// Block = 4 waves, 64 rows. Wave: 16 rows x 128 cols via 8 N-tiles of 16x16x32 MFMA.
template <int K, bool INF16>
__global__ __launch_bounds__(256, 1) void gemm_node(const void* __restrict__ inp,
                                                    const float* __restrict__ WL,
                                                    const float* __restrict__ WR,
                                                    _Float16* __restrict__ outP) {
    __shared__ __align__(16) _Float16 wt[128 * K];       // B^T: [n][k]
    __shared__ __align__(16) _Float16 at[4][16 * 128];   // per-wave A stage / C repack

    int tid = threadIdx.x;
    for (int i = tid; i < K * 64; i += 256) {
        int k = i >> 6, n = i & 63;
        wt[n * K + k]        = (_Float16)WL[i];
        wt[(64 + n) * K + k] = (_Float16)WR[i];
    }
    __syncthreads();

    int wave = tid >> 6, lane = tid & 63;
    int g = lane >> 4, r = lane & 15;

    half8 bf[8][K / 32];
#pragma unroll
    for (int nt = 0; nt < 8; ++nt)
#pragma unroll
        for (int ks = 0; ks < K / 32; ++ks)
            bf[nt][ks] = *(const half8*)&wt[(nt * 16 + r) * K + ks * 32 + g * 8];

    int rowbase = blockIdx.x * 64 + wave * 16;
    int eq = lane >> 2, qq = lane & 3;
    int srow = rowbase + eq;
    if (srow > NN - 1) srow = NN - 1;
    _Float16* A = &at[wave][0];

    if constexpr (!INF16) {
        const float* sr = (const float*)inp + (size_t)srow * K + qq * (K / 4);
        unsigned int pk[K / 8];
#pragma unroll
        for (int i = 0; i < K / 16; ++i) {
            float4 v = ((const float4*)sr)[i];
            pk[2 * i]     = pk2(v.x, v.y);
            pk[2 * i + 1] = pk2(v.z, v.w);
        }
        unsigned int* da = (unsigned int*)(A + eq * K + qq * (K / 4));
#pragma unroll
        for (int i = 0; i < K / 32; ++i)
            ((uint4*)da)[i] = make_uint4(pk[4 * i], pk[4 * i + 1], pk[4 * i + 2], pk[4 * i + 3]);
    } else {
        const _Float16* sr = (const _Float16*)inp + (size_t)srow * K + qq * (K / 4);
        uint4* da = (uint4*)(A + eq * K + qq * (K / 4));
#pragma unroll
        for (int i = 0; i < K / 32; ++i)
            da[i] = ((const uint4*)sr)[i];
    }

    f32x4 acc[8];
#pragma unroll
    for (int nt = 0; nt < 8; ++nt) acc[nt] = f32x4{0.f, 0.f, 0.f, 0.f};
#pragma unroll
    for (int ks = 0; ks < K / 32; ++ks) {
        half8 af = *(const half8*)(A + r * K + ks * 32 + g * 8);
#pragma unroll
        for (int nt = 0; nt < 8; ++nt)
            acc[nt] = __builtin_amdgcn_mfma_f32_16x16x32_f16(af, bf[nt][ks], acc[nt], 0, 0, 0);
    }

    // repack C to [16][128] f16 in LDS, then vector-store
#pragma unroll
    for (int nt = 0; nt < 8; ++nt)
#pragma unroll
        for (int rr = 0; rr < 4; ++rr)
            A[(g * 4 + rr) * 128 + nt * 16 + r] = (_Float16)acc[nt][rr];
    __syncthreads();
#pragma unroll
    for (int it = 0; it < 2; ++it) {
        int lrow = it * 8 + (lane >> 3);
        int cc = (lane & 7) * 16;
        int grow = rowbase + lrow;
        if (grow < NN) {
            uint4 u0 = *(const uint4*)&A[lrow * 128 + cc];
            uint4 u1 = *(const uint4*)&A[lrow * 128 + cc + 8];
            *(uint4*)&outP[(size_t)grow * 128 + cc] = u0;
            *(uint4*)&outP[(size_t)grow * 128 + cc + 8] = u1;
        }
    }
}

// ---------------- gather-reduce over CSR (f16 input, stride 128, cols 0..63) ----------------
__global__ __launch_bounds__(256) void gather_f16(const _Float16* __restrict__ v, const int* __restrict__ csr,
                                                  const int* __restrict__ offs, const int* __restrict__ degi,
                                                  float* __restrict__ agg) {
    int tid = threadIdx.x;
    int node = blockIdx.x * 4 + (tid >> 6);
    int lane = tid & 63;
    if (node >= NN) return;
    int h0 = lane >> 5, c = lane & 31;
    int off = offs[node], cnt = degi[node];
    float a0 = 0.f, a1 = 0.f;
    int j = 0;
    for (; j + 4 <= cnt; j += 4) {
        int r0 = csr[off + j + h0];
        int r1 = csr[off + j + 2 + h0];
        unsigned int u0 = *(const unsigned int*)&v[(size_t)r0 * 128 + 2 * c];
        unsigned int u1 = *(const unsigned int*)&v[(size_t)r1 * 128 + 2 * c];
        a0 += f16lo(u0); a1 += f16hi(u0);
        a0 += f16lo(u1); a1 += f16hi(u1);
    }
    for (; j + 2 <= cnt; j += 2) {
        int r0 = csr[off + j + h0];
        unsigned int u0 = *(const unsigned int*)&v[(size_t)r0 * 128 + 2 * c];
        a0 += f16lo(u0); a1 += f16hi(u0);
    }
    if (j < cnt && h0 == 0) {
        int r0 = csr[off + j];
        unsigned int u0 = *(const unsigned int*)&v[(size_t)r0 * 128 + 2 * c];
        a0 += f16lo(u0); a1 += f16hi(u0);
    }
    a0 += __shfl_xor(a0, 32, 64);
    a1 += __shfl_xor(a1, 32, 64);
    if (h0 == 0) {
        float2 o; o.x = a0; o.y = a1;
        *(float2*)&agg[(size_t)node * 64 + 2 * c] = o;
    }
}

// ---------------- fused mean + bl + proj + LayerNorm + ReLU -> f16 h ----------------
__global__ __launch_bounds__(256) void ln_elem(const float* __restrict__ agg, const int* __restrict__ degi,
                                               const _Float16* __restrict__ proj,   // bufP, cols 64..127
                                               const float* __restrict__ bl, const float* __restrict__ g,
                                               const float* __restrict__ be, _Float16* __restrict__ out) {
    int tid = threadIdx.x;
    int wave = tid >> 6, lane = tid & 63;
    int h0 = lane >> 5, c = lane & 31;
    int node = blockIdx.x * 8 + wave * 2 + h0;
    if (node >= NN) return;
    unsigned int up = *(const unsigned int*)&proj[(size_t)node * 128 + 64 + 2 * c];
    float p0 = f16lo(up), p1 = f16hi(up);
    float2 ag = *(const float2*)&agg[(size_t)node * 64 + 2 * c];
    float dg = (float)degi[node];
    dg = dg < 1.f ? 1.f : dg;
    float v0 = ag.x / dg + bl[2 * c] + p0;
    float v1 = ag.y / dg + bl[2 * c + 1] + p1;
    float s = v0 + v1, s2 = v0 * v0 + v1 * v1;
#pragma unroll
    for (int o = 16; o > 0; o >>= 1) {
        s  += __shfl_xor(s, o, 64);
        s2 += __shfl_xor(s2, o, 64);
    }
    float mu = s * (1.f / 64.f);
    float var = s2 * (1.f / 64.f) - mu * mu;
    float rs = rsqrtf(var + 1e-5f);
    float h0v = (v0 - mu) * rs * g[2 * c] + be[2 * c];
    float h1v = (v1 - mu) * rs * g[2 * c + 1] + be[2 * c + 1];
    h0v = h0v > 0.f ? h0v : 0.f;
    h1v = h1v > 0.f ? h1v : 0.f;
    *(unsigned int*)&out[(size_t)node * 64 + 2 * c] = pk2(h0v, h1v);
}

// ---------------- edge MLP via f16 MFMA (h is f16) ----------------
#define NTILES 15625   // 1M / 64 edges per block-tile
__global__ __launch_bounds__(256) void edge_mlp_mfma(const _Float16* __restrict__ h,
                                                     const int* __restrict__ src,
                                                     const int* __restrict__ dst,
                                                     const float* __restrict__ ea,
                                                     const float* __restrict__ W1,
                                                     const float* __restrict__ b1,
                                                     const float* __restrict__ W2,
                                                     const float* __restrict__ b2,
                                                     const float* __restrict__ W3,
                                                     const float* __restrict__ b3,
                                                     float* __restrict__ out) {
    __shared__ __align__(16) _Float16 w1t[64 * 160];
    __shared__ __align__(16) _Float16 w2t[32 * 64];
    __shared__ __align__(16) _Float16 atile[4][16 * 160];
    __shared__ __align__(16) _Float16 z1t[4][16 * 72];

    int tid = threadIdx.x;
    for (int i = tid; i < 64 * 160 / 2; i += 256) ((unsigned int*)w1t)[i] = 0u;
    __syncthreads();
    for (int i = tid; i < 144 * 64; i += 256) {
        int k = i >> 6, n = i & 63;
        w1t[n * 160 + k] = (_Float16)W1[i];
    }
    for (int i = tid; i < 64 * 32; i += 256) {
        int k = i >> 5, n = i & 31;
        w2t[n * 64 + k] = (_Float16)W2[i];
    }
    __syncthreads();

    int wave = tid >> 6;
    int lane = tid & 63;
    int g = lane >> 4;
    int r = lane & 15;

    half8 b1f[4][5];
#pragma unroll
    for (int nt = 0; nt < 4; ++nt)
#pragma unroll
        for (int ks = 0; ks < 5; ++ks)
            b1f[nt][ks] = *(const half8*)&w1t[(nt * 16 + r) * 160 + ks * 32 + g * 8];
    half8 b2f[2][2];
#pragma unroll
    for (int nt = 0; nt < 2; ++nt)
#pragma unroll
        for (int ks = 0; ks < 2; ++ks)
            b2f[nt][ks] = *(const half8*)&w2t[(nt * 16 + r) * 64 + ks * 32 + g * 8];

    float b1c0 = b1[0 * 16 + r], b1c1 = b1[1 * 16 + r], b1c2 = b1[2 * 16 + r], b1c3 = b1[3 * 16 + r];
    float b2c0 = b2[0 * 16 + r], b2c1 = b2[1 * 16 + r];
    float w3c0 = W3[0 * 16 + r], w3c1 = W3[1 * 16 + r];
    float b3v = b3[0];

    _Float16* A = &atile[wave][0];
    _Float16* Z = &z1t[wave][0];
    int eq = lane >> 2;
    int qq = lane & 3;

    for (int t = blockIdx.x; t < NTILES; t += gridDim.x) {
        int ebase = t * 64 + wave * 16;
        int e = ebase + eq;
        int s = src[e];
        int d = dst[e];

        // ---- stage A: [h_s(64) | h_d(64) | ea(16) | 0(16)] f16 ----
        const _Float16* srow = (qq < 2) ? (h + (size_t)s * 64 + qq * 32)
                                        : (h + (size_t)d * 64 + (qq - 2) * 32);
        uint4* da = (uint4*)(A + eq * 160 + qq * 32);
#pragma unroll
        for (int i = 0; i < 4; ++i) da[i] = ((const uint4*)srow)[i];
        float4 av = *(const float4*)(ea + (size_t)e * 16 + qq * 4);
        uint2 eapk; eapk.x = pk2(av.x, av.y); eapk.y = pk2(av.z, av.w);
        *(uint2*)(A + eq * 160 + 128 + qq * 4) = eapk;
        uint2 zz; zz.x = 0u; zz.y = 0u;
        *(uint2*)(A + eq * 160 + 144 + qq * 4) = zz;

        // ---- layer 1 ----
        f32x4 c1_0 = {b1c0, b1c0, b1c0, b1c0};
        f32x4 c1_1 = {b1c1, b1c1, b1c1, b1c1};
        f32x4 c1_2 = {b1c2, b1c2, b1c2, b1c2};
        f32x4 c1_3 = {b1c3, b1c3, b1c3, b1c3};
#pragma unroll
        for (int ks = 0; ks < 5; ++ks) {
            half8 af = *(const half8*)(A + r * 160 + ks * 32 + g * 8);
            c1_0 = __builtin_amdgcn_mfma_f32_16x16x32_f16(af, b1f[0][ks], c1_0, 0, 0, 0);
            c1_1 = __builtin_amdgcn_mfma_f32_16x16x32_f16(af, b1f[1][ks], c1_1, 0, 0, 0);
            c1_2 = __builtin_amdgcn_mfma_f32_16x16x32_f16(af, b1f[2][ks], c1_2, 0, 0, 0);
            c1_3 = __builtin_amdgcn_mfma_f32_16x16x32_f16(af, b1f[3][ks], c1_3, 0, 0, 0);
        }
#pragma unroll
        for (int rr = 0; rr < 4; ++rr) {
            float v0 = c1_0[rr]; v0 = v0 > 0.f ? v0 : 0.f;
            float v1 = c1_1[rr]; v1 = v1 > 0.f ? v1 : 0.f;
            float v2 = c1_2[rr]; v2 = v2 > 0.f ? v2 : 0.f;
            float v3 = c1_3[rr]; v3 = v3 > 0.f ? v3 : 0.f;
            int row = g * 4 + rr;
            Z[row * 72 + 0 * 16 + r] = (_Float16)v0;
            Z[row * 72 + 1 * 16 + r] = (_Float16)v1;
            Z[row * 72 + 2 * 16 + r] = (_Float16)v2;
            Z[row * 72 + 3 * 16 + r] = (_Float16)v3;
        }

        // ---- layer 2 ----
        f32x4 c2_0 = {b2c0, b2c0, b2c0, b2c0};
        f32x4 c2_1 = {b2c1, b2c1, b2c1, b2c1};
#pragma unroll
        for (int ks = 0; ks < 2; ++ks) {
            half8 a2 = *(const half8*)(Z + r * 72 + ks * 32 + g * 8);
            c2_0 = __builtin_amdgcn_mfma_f32_16x16x32_f16(a2, b2f[0][ks], c2_0, 0, 0, 0);
            c2_1 = __builtin_amdgcn_mfma_f32_16x16x32_f16(a2, b2f[1][ks], c2_1, 0, 0, 0);
        }

        // ---- layer 3 ----
        float t0, t1, t2, t3;
        {
            float u0, u1;
            u0 = c2_0[0]; u0 = u0 > 0.f ? u0 : 0.f;
            u1 = c2_1[0]; u1 = u1 > 0.f ? u1 : 0.f;
            t0 = u0 * w3c0 + u1 * w3c1;
            u0 = c2_0[1]; u0 = u0 > 0.f ? u0 : 0.f;
            u1 = c2_1[1]; u1 = u1 > 0.f ? u1 : 0.f;
            t1 = u0 * w3c0 + u1 * w3c1;
            u0 = c2_0[2]; u0 = u0 > 0.f ? u0 : 0.f;
            u1 = c2_1[2]; u1 = u1 > 0.f ? u1 : 0.f;
            t2 = u0 * w3c0 + u1 * w3c1;
            u0 = c2_0[3]; u0 = u0 > 0.f ? u0 : 0.f;
            u1 = c2_1[3]; u1 = u1 > 0.f ? u1 : 0.f;
            t3 = u0 * w3c0 + u1 * w3c1;
        }
#pragma unroll
        for (int m = 1; m < 16; m <<= 1) {
            t0 += __shfl_xor(t0, m, 64);
            t1 += __shfl_xor(t1, m, 64);
            t2 += __shfl_xor(t2, m, 64);
            t3 += __shfl_xor(t3, m, 64);
        }
        if (r == 0) out[ebase + g * 4 + 0] = t0 + b3v;
        if (r == 1) out[ebase + g * 4 + 1] = t1 + b3v;
        if (r == 2) out[ebase + g * 4 + 2] = t2 + b3v;
        if (r == 3) out[ebase + g * 4 + 3] = t3 + b3v;
    }
}

// ---------------- workspace layout (bytes) ----------------
#define WS_AGG   0                    // f32 100K*64           = 25,600,000
#define WS_BUFP  25600000             // f16 100K*128          = 25,600,000
#define WS_BUFH  51200000             // f16 100K*64           = 12,800,000
#define WS_DEGI  64000000             // int 100K              =    400,000
#define WS_OFFS  64400000             // int 100K              =    400,000
#define WS_CSR   64800000             // int 1M                =  4,000,000
#define WS_NEED  68800000

extern "C" void kernel_launch(void* const* d_in, const int* in_sizes, int n_in,
                              void* d_out, int out_size, void* d_ws, size_t ws_size,
                              hipStream_t stream) {
    const float* x   = (const float*)d_in[0];
    const int*   ei  = (const int*)d_in[1];
    const float* ea  = (const float*)d_in[2];
    const float* Wl0 = (const float*)d_in[3];
    const float* bl0 = (const float*)d_in[4];
    const float* Wr0 = (const float*)d_in[5];
    const float* g0  = (const float*)d_in[6];
    const float* be0 = (const float*)d_in[7];
    const float* Wl1 = (const float*)d_in[8];
    const float* bl1 = (const float*)d_in[9];
    const float* Wr1 = (const float*)d_in[10];
    const float* g1  = (const float*)d_in[11];
    const float* be1 = (const float*)d_in[12];
    const float* W1  = (const float*)d_in[13];
    const float* b1  = (const float*)d_in[14];
    const float* W2  = (const float*)d_in[15];
    const float* b2  = (const float*)d_in[16];
    const float* W3  = (const float*)d_in[17];
    const float* b3  = (const float*)d_in[18];
    float* out = (float*)d_out;

    const int* src  = ei;
    const int* dstp = ei + NE;

    char* ws = (char*)d_ws;
    float*     agg  = (float*)(ws + WS_AGG);
    _Float16*  bufP = (_Float16*)(ws + WS_BUFP);
    _Float16*  bufH = (_Float16*)(ws + WS_BUFH);
    int*       degi = (int*)(ws + WS_DEGI);
    int*       offs = (int*)(ws + WS_OFFS);
    int*       csr  = (int*)(ws + WS_CSR);
    int*       cursor = (int*)(ws + WS_AGG);        // aliases agg (dead until gather0)
    int*       bsum   = (int*)(ws + WS_BUFP);       // aliases bufP (dead until gemm0)
    int*       boff   = (int*)(ws + WS_BUFP + 4096);

    hipMemsetAsync(degi, 0, 400000, stream);
    deg_int_kernel<<<(NE + 255) / 256, 256, 0, stream>>>(dstp, degi);
    scan_partial<<<196, 256, 0, stream>>>(degi, bsum);
    scan_spine<<<1, 256, 0, stream>>>(bsum, boff);
    scan_final<<<196, 512, 0, stream>>>(degi, boff, offs, cursor);
    csr_fill<<<(NE + 255) / 256, 256, 0, stream>>>(src, dstp, cursor, csr);

    const int gemm_grid = (NN + 63) / 64;   // 1563
    // ---- layer 0 ----
    gemm_node<128, false><<<gemm_grid, 256, 0, stream>>>(x, Wl0, Wr0, bufP);
    gather_f16<<<NN / 4, 256, 0, stream>>>(bufP, csr, offs, degi, agg);
    ln_elem<<<(NN + 7) / 8, 256, 0, stream>>>(agg, degi, bufP, bl0, g0, be0, bufH);

    // ---- layer 1 ----
    gemm_node<64, true><<<gemm_grid, 256, 0, stream>>>(bufH, Wl1, Wr1, bufP);
    gather_f16<<<NN / 4, 256, 0, stream>>>(bufP, csr, offs, degi, agg);
    ln_elem<<<(NN + 7) / 8, 256, 0, stream>>>(agg, degi, bufP, bl1, g1, be1, bufH);

    // ---- edge MLP ----
    edge_mlp_mfma<<<3125, 256, 0, stream>>>(bufH, src, dstp, ea,
                                            W1, b1, W2, b2, W3, b3, out);
}

// Round 7
// 586.062 us; speedup vs baseline: 2.9782x; 1.0049x over previous
//
#include <hip/hip_runtime.h>
#include <hip/hip_bf16.h>

#define NN 100000
#define NE 1000000

typedef _Float16 half8  __attribute__((ext_vector_type(8)));
typedef float    f32x4  __attribute__((ext_vector_type(4)));

__device__ inline unsigned int pk2(float a, float b) {
    auto h = __builtin_amdgcn_cvt_pkrtz(a, b);   // __fp16 ext_vector(2)
    return __builtin_bit_cast(unsigned int, h);
}
__device__ inline float f16lo(unsigned int u) {
    return (float)__builtin_bit_cast(_Float16, (unsigned short)(u & 0xffffu));
}
__device__ inline float f16hi(unsigned int u) {
    return (float)__builtin_bit_cast(_Float16, (unsigned short)(u >> 16));
}

// ---------------- int degree histogram ----------------
__global__ __launch_bounds__(256) void deg_int_kernel(const int* __restrict__ dst, int* __restrict__ degi) {
    int e = blockIdx.x * 256 + threadIdx.x;
    if (e < NE) atomicAdd(&degi[dst[e]], 1);
}

// ---------------- scan A ----------------
__global__ __launch_bounds__(256) void scan_partial(const int* __restrict__ degi, int* __restrict__ bs) {
    __shared__ int sd[256];
    int b = blockIdx.x, t = threadIdx.x;
    int i = b * 512 + t;
    int v = (i < NN ? degi[i] : 0) + (i + 256 < NN ? degi[i + 256] : 0);
    sd[t] = v;
    __syncthreads();
    for (int o = 128; o > 0; o >>= 1) {
        if (t < o) sd[t] += sd[t + o];
        __syncthreads();
    }
    if (t == 0) bs[b] = sd[0];
}

// ---------------- scan B ----------------
__global__ __launch_bounds__(256) void scan_spine(const int* __restrict__ bs, int* __restrict__ bo) {
    __shared__ int sd[256];
    int t = threadIdx.x;
    int v = (t < 196) ? bs[t] : 0;
    sd[t] = v;
    __syncthreads();
    for (int o = 1; o < 256; o <<= 1) {
        int add = (t >= o) ? sd[t - o] : 0;
        __syncthreads();
        sd[t] += add;
        __syncthreads();
    }
    if (t < 196) bo[t] = sd[t] - v;
}

// ---------------- scan C ----------------
__global__ __launch_bounds__(512) void scan_final(const int* __restrict__ degi, const int* __restrict__ bo,
                                                  int* __restrict__ offs, int* __restrict__ cursor) {
    __shared__ int sd[512];
    int b = blockIdx.x, t = threadIdx.x;
    int i = b * 512 + t;
    int v = (i < NN) ? degi[i] : 0;
    sd[t] = v;
    __syncthreads();
    for (int o = 1; o < 512; o <<= 1) {
        int add = (t >= o) ? sd[t - o] : 0;
        __syncthreads();
        sd[t] += add;
        __syncthreads();
    }
    if (i < NN) {
        int ex = bo[b] + sd[t] - v;
        offs[i] = ex;
        cursor[i] = ex;
    }
}

// ---------------- CSR fill ----------------
__global__ __launch_bounds__(256) void csr_fill(const int* __restrict__ src, const int* __restrict__ dst,
                                                int* __restrict__ cursor, int* __restrict__ csr) {
    int e = blockIdx.x * 256 + threadIdx.x;
    if (e < NE) {
        int pos = atomicAdd(&cursor[dst[e]], 1);
        csr[pos] = src[e];
    }
}

// ---------------- node GEMM: [projL | projR] = in[n,:K] @ [WL | WR] (f16 out, padded LDS) ----------------
template <int K, bool INF16>
__global__ __launch_bounds__(256, 1) void gemm_node(const void* __restrict__ inp,
                                                    const float* __restrict__ WL,
                                                    const float* __restrict__ WR,
                                                    _Float16* __restrict__ outL,
                                                    _Float16* __restrict__ outR) {
    __shared__ __align__(16) _Float16 wt[128 * K];       // B^T: [n][k]
    __shared__ __align__(16) _Float16 at[4][16 * 136];   // per-wave A stage / C repack, stride 136

    int tid = threadIdx.x;
    for (int i = tid; i < K * 64; i += 256) {
        int k = i >> 6, n = i & 63;
        wt[n * K + k]        = (_Float16)WL[i];
        wt[(64 + n) * K + k] = (_Float16)WR[i];
    }
    __syncthreads();

    int wave = tid >> 6, lane = tid & 63;
    int g = lane >> 4, r = lane & 15;

    half8 bf[8][K / 32];
#pragma unroll
    for (int nt = 0; nt < 8; ++nt)
#pragma unroll
        for (int ks = 0; ks < K / 32; ++ks)
            bf[nt][ks] = *(const half8*)&wt[(nt * 16 + r) * K + ks * 32 + g * 8];

    int rowbase = blockIdx.x * 64 + wave * 16;
    int eq = lane >> 2, qq = lane & 3;
    int srow = rowbase + eq;
    if (srow > NN - 1) srow = NN - 1;
    _Float16* A = &at[wave][0];

    if constexpr (!INF16) {
        const float* sr = (const float*)inp + (size_t)srow * K + qq * (K / 4);
        unsigned int pk[K / 8];
#pragma unroll
        for (int i = 0; i < K / 16; ++i) {
            float4 v = ((const float4*)sr)[i];
            pk[2 * i]     = pk2(v.x, v.y);
            pk[2 * i + 1] = pk2(v.z, v.w);
        }
        unsigned int* da = (unsigned int*)(A + eq * 136 + qq * (K / 4));
#pragma unroll
        for (int i = 0; i < K / 32; ++i)
            ((uint4*)da)[i] = make_uint4(pk[4 * i], pk[4 * i + 1], pk[4 * i + 2], pk[4 * i + 3]);
    } else {
        const _Float16* sr = (const _Float16*)inp + (size_t)srow * K + qq * (K / 4);
        uint4* da = (uint4*)(A + eq * 136 + qq * (K / 4));
#pragma unroll
        for (int i = 0; i < K / 32; ++i)
            da[i] = ((const uint4*)sr)[i];
    }

    f32x4 acc[8];
#pragma unroll
    for (int nt = 0; nt < 8; ++nt) acc[nt] = f32x4{0.f, 0.f, 0.f, 0.f};
#pragma unroll
    for (int ks = 0; ks < K / 32; ++ks) {
        half8 af = *(const half8*)(A + r * 136 + ks * 32 + g * 8);
#pragma unroll
        for (int nt = 0; nt < 8; ++nt)
            acc[nt] = __builtin_amdgcn_mfma_f32_16x16x32_f16(af, bf[nt][ks], acc[nt], 0, 0, 0);
    }

    // repack C to [16][136] f16 in LDS, then split vector-store
#pragma unroll
    for (int nt = 0; nt < 8; ++nt)
#pragma unroll
        for (int rr = 0; rr < 4; ++rr)
            A[(g * 4 + rr) * 136 + nt * 16 + r] = (_Float16)acc[nt][rr];
    __syncthreads();
#pragma unroll
    for (int it = 0; it < 2; ++it) {
        int lrow = it * 8 + (lane >> 3);
        int cc = (lane & 7) * 16;
        int grow = rowbase + lrow;
        if (grow < NN) {
            uint4 u0 = *(const uint4*)&A[lrow * 136 + cc];
            uint4 u1 = *(const uint4*)&A[lrow * 136 + cc + 8];
            if (cc < 64) {
                *(uint4*)&outL[(size_t)grow * 64 + cc] = u0;
                *(uint4*)&outL[(size_t)grow * 64 + cc + 8] = u1;
            } else {
                *(uint4*)&outR[(size_t)grow * 64 + cc - 64] = u0;
                *(uint4*)&outR[(size_t)grow * 64 + cc - 56] = u1;
            }
        }
    }
}

// ---------------- fused gather-reduce + mean + bl + proj + LayerNorm + ReLU -> f16 h ----------------
__global__ __launch_bounds__(256) void gather_ln(const _Float16* __restrict__ vL,
                                                 const _Float16* __restrict__ pR,
                                                 const int* __restrict__ csr,
                                                 const int* __restrict__ offs,
                                                 const int* __restrict__ degi,
                                                 const float* __restrict__ bl,
                                                 const float* __restrict__ g,
                                                 const float* __restrict__ be,
                                                 _Float16* __restrict__ out) {
    int tid = threadIdx.x;
    int node = blockIdx.x * 4 + (tid >> 6);
    int lane = tid & 63;
    if (node >= NN) return;
    int h0 = lane >> 5, c = lane & 31;
    int off = offs[node], cnt = degi[node];
    float a0 = 0.f, a1 = 0.f;
    int j = 0;
    for (; j + 4 <= cnt; j += 4) {
        int r0 = csr[off + j + h0];
        int r1 = csr[off + j + 2 + h0];
        unsigned int u0 = *(const unsigned int*)&vL[(size_t)r0 * 64 + 2 * c];
        unsigned int u1 = *(const unsigned int*)&vL[(size_t)r1 * 64 + 2 * c];
        a0 += f16lo(u0); a1 += f16hi(u0);
        a0 += f16lo(u1); a1 += f16hi(u1);
    }
    for (; j + 2 <= cnt; j += 2) {
        int r0 = csr[off + j + h0];
        unsigned int u0 = *(const unsigned int*)&vL[(size_t)r0 * 64 + 2 * c];
        a0 += f16lo(u0); a1 += f16hi(u0);
    }
    if (j < cnt && h0 == 0) {
        int r0 = csr[off + j];
        unsigned int u0 = *(const unsigned int*)&vL[(size_t)r0 * 64 + 2 * c];
        a0 += f16lo(u0); a1 += f16hi(u0);
    }
    a0 += __shfl_xor(a0, 32, 64);
    a1 += __shfl_xor(a1, 32, 64);

    // mean/bias/proj
    float dg = (float)cnt;
    dg = dg < 1.f ? 1.f : dg;
    float2 blv = *(const float2*)&bl[2 * c];
    unsigned int up = *(const unsigned int*)&pR[(size_t)node * 64 + 2 * c];
    float v0 = a0 / dg + blv.x + f16lo(up);
    float v1 = a1 / dg + blv.y + f16hi(up);
    // LayerNorm over 64 channels (c dimension)
    float s = v0 + v1, s2 = v0 * v0 + v1 * v1;
#pragma unroll
    for (int o = 16; o > 0; o >>= 1) {
        s  += __shfl_xor(s, o, 64);
        s2 += __shfl_xor(s2, o, 64);
    }
    float mu = s * (1.f / 64.f);
    float var = s2 * (1.f / 64.f) - mu * mu;
    float rs = rsqrtf(var + 1e-5f);
    float2 gv  = *(const float2*)&g[2 * c];
    float2 bev = *(const float2*)&be[2 * c];
    float h0v = (v0 - mu) * rs * gv.x + bev.x;
    float h1v = (v1 - mu) * rs * gv.y + bev.y;
    h0v = h0v > 0.f ? h0v : 0.f;
    h1v = h1v > 0.f ? h1v : 0.f;
    if (h0 == 0) *(unsigned int*)&out[(size_t)node * 64 + 2 * c] = pk2(h0v, h1v);
}

// ---------------- edge MLP via f16 MFMA (padded + aliased LDS) ----------------
#define NTILES 15625   // 1M / 64 edges per block-tile
#define ASTR 168       // padded A row stride (f16): 168*2=336 B -> r*84 mod 32 spreads 8-ways
__global__ __launch_bounds__(256) void edge_mlp_mfma(const _Float16* __restrict__ h,
                                                     const int* __restrict__ src,
                                                     const int* __restrict__ dst,
                                                     const float* __restrict__ ea,
                                                     const float* __restrict__ W1,
                                                     const float* __restrict__ b1,
                                                     const float* __restrict__ W2,
                                                     const float* __restrict__ b2,
                                                     const float* __restrict__ W3,
                                                     const float* __restrict__ b3,
                                                     float* __restrict__ out) {
    // stage area (24576 B) aliases compute area (30720 B): barrier-separated
    __shared__ __align__(16) char smem[30720];
    _Float16* w1t = (_Float16*)smem;            // [64][160]  20480 B
    _Float16* w2t = (_Float16*)(smem + 20480);  // [32][64]    4096 B

    int tid = threadIdx.x;
    for (int i = tid; i < 64 * 160 / 2; i += 256) ((unsigned int*)w1t)[i] = 0u;
    __syncthreads();
    for (int i = tid; i < 144 * 64; i += 256) {
        int k = i >> 6, n = i & 63;
        w1t[n * 160 + k] = (_Float16)W1[i];
    }
    for (int i = tid; i < 64 * 32; i += 256) {
        int k = i >> 5, n = i & 31;
        w2t[n * 64 + k] = (_Float16)W2[i];
    }
    __syncthreads();

    int wave = tid >> 6;
    int lane = tid & 63;
    int g = lane >> 4;
    int r = lane & 15;

    half8 b1f[4][5];
#pragma unroll
    for (int nt = 0; nt < 4; ++nt)
#pragma unroll
        for (int ks = 0; ks < 5; ++ks)
            b1f[nt][ks] = *(const half8*)&w1t[(nt * 16 + r) * 160 + ks * 32 + g * 8];
    half8 b2f[2][2];
#pragma unroll
    for (int nt = 0; nt < 2; ++nt)
#pragma unroll
        for (int ks = 0; ks < 2; ++ks)
            b2f[nt][ks] = *(const half8*)&w2t[(nt * 16 + r) * 64 + ks * 32 + g * 8];
    __syncthreads();   // weight-stage LDS is dead from here; alias as A/Z tiles

    _Float16* A = (_Float16*)(smem + wave * (16 * ASTR * 2));          // 5376 B/wave
    _Float16* Z = (_Float16*)(smem + 4 * (16 * ASTR * 2) + wave * (16 * 72 * 2)); // 2304 B/wave

    float b1c0 = b1[0 * 16 + r], b1c1 = b1[1 * 16 + r], b1c2 = b1[2 * 16 + r], b1c3 = b1[3 * 16 + r];
    float b2c0 = b2[0 * 16 + r], b2c1 = b2[1 * 16 + r];
    float w3c0 = W3[0 * 16 + r], w3c1 = W3[1 * 16 + r];
    float b3v = b3[0];

    int eq = lane >> 2;
    int qq = lane & 3;

    for (int t = blockIdx.x; t < NTILES; t += gridDim.x) {
        int ebase = t * 64 + wave * 16;
        int e = ebase + eq;
        int s = src[e];
        int d = dst[e];

        // ---- stage A: [h_s(64) | h_d(64) | ea(16) | 0(16)] f16, stride ASTR ----
        const _Float16* srow = (qq < 2) ? (h + (size_t)s * 64 + qq * 32)
                                        : (h + (size_t)d * 64 + (qq - 2) * 32);
        uint4* da = (uint4*)(A + eq * ASTR + qq * 32);
#pragma unroll
        for (int i = 0; i < 4; ++i) da[i] = ((const uint4*)srow)[i];
        float4 av = *(const float4*)(ea + (size_t)e * 16 + qq * 4);
        uint2 eapk; eapk.x = pk2(av.x, av.y); eapk.y = pk2(av.z, av.w);
        *(uint2*)(A + eq * ASTR + 128 + qq * 4) = eapk;
        uint2 zz; zz.x = 0u; zz.y = 0u;
        *(uint2*)(A + eq * ASTR + 144 + qq * 4) = zz;

        // ---- layer 1 ----
        f32x4 c1_0 = {b1c0, b1c0, b1c0, b1c0};
        f32x4 c1_1 = {b1c1, b1c1, b1c1, b1c1};
        f32x4 c1_2 = {b1c2, b1c2, b1c2, b1c2};
        f32x4 c1_3 = {b1c3, b1c3, b1c3, b1c3};
#pragma unroll
        for (int ks = 0; ks < 5; ++ks) {
            half8 af = *(const half8*)(A + r * ASTR + ks * 32 + g * 8);
            c1_0 = __builtin_amdgcn_mfma_f32_16x16x32_f16(af, b1f[0][ks], c1_0, 0, 0, 0);
            c1_1 = __builtin_amdgcn_mfma_f32_16x16x32_f16(af, b1f[1][ks], c1_1, 0, 0, 0);
            c1_2 = __builtin_amdgcn_mfma_f32_16x16x32_f16(af, b1f[2][ks], c1_2, 0, 0, 0);
            c1_3 = __builtin_amdgcn_mfma_f32_16x16x32_f16(af, b1f[3][ks], c1_3, 0, 0, 0);
        }
#pragma unroll
        for (int rr = 0; rr < 4; ++rr) {
            float v0 = c1_0[rr]; v0 = v0 > 0.f ? v0 : 0.f;
            float v1 = c1_1[rr]; v1 = v1 > 0.f ? v1 : 0.f;
            float v2 = c1_2[rr]; v2 = v2 > 0.f ? v2 : 0.f;
            float v3 = c1_3[rr]; v3 = v3 > 0.f ? v3 : 0.f;
            int row = g * 4 + rr;
            Z[row * 72 + 0 * 16 + r] = (_Float16)v0;
            Z[row * 72 + 1 * 16 + r] = (_Float16)v1;
            Z[row * 72 + 2 * 16 + r] = (_Float16)v2;
            Z[row * 72 + 3 * 16 + r] = (_Float16)v3;
        }

        // ---- layer 2 ----
        f32x4 c2_0 = {b2c0, b2c0, b2c0, b2c0};
        f32x4 c2_1 = {b2c1, b2c1, b2c1, b2c1};
#pragma unroll
        for (int ks = 0; ks < 2; ++ks) {
            half8 a2 = *(const half8*)(Z + r * 72 + ks * 32 + g * 8);
            c2_0 = __builtin_amdgcn_mfma_f32_16x16x32_f16(a2, b2f[0][ks], c2_0, 0, 0, 0);
            c2_1 = __builtin_amdgcn_mfma_f32_16x16x32_f16(a2, b2f[1][ks], c2_1, 0, 0, 0);
        }

        // ---- layer 3 ----
        float t0, t1, t2, t3;
        {
            float u0, u1;
            u0 = c2_0[0]; u0 = u0 > 0.f ? u0 : 0.f;
            u1 = c2_1[0]; u1 = u1 > 0.f ? u1 : 0.f;
            t0 = u0 * w3c0 + u1 * w3c1;
            u0 = c2_0[1]; u0 = u0 > 0.f ? u0 : 0.f;
            u1 = c2_1[1]; u1 = u1 > 0.f ? u1 : 0.f;
            t1 = u0 * w3c0 + u1 * w3c1;
            u0 = c2_0[2]; u0 = u0 > 0.f ? u0 : 0.f;
            u1 = c2_1[2]; u1 = u1 > 0.f ? u1 : 0.f;
            t2 = u0 * w3c0 + u1 * w3c1;
            u0 = c2_0[3]; u0 = u0 > 0.f ? u0 : 0.f;
            u1 = c2_1[3]; u1 = u1 > 0.f ? u1 : 0.f;
            t3 = u0 * w3c0 + u1 * w3c1;
        }
#pragma unroll
        for (int m = 1; m < 16; m <<= 1) {
            t0 += __shfl_xor(t0, m, 64);
            t1 += __shfl_xor(t1, m, 64);
            t2 += __shfl_xor(t2, m, 64);
            t3 += __shfl_xor(t3, m, 64);
        }
        if (r == 0) out[ebase + g * 4 + 0] = t0 + b3v;
        if (r == 1) out[ebase + g * 4 + 1] = t1 + b3v;
        if (r == 2) out[ebase + g * 4 + 2] = t2 + b3v;
        if (r == 3) out[ebase + g * 4 + 3] = t3 + b3v;
    }
}

// ---------------- workspace layout (bytes) ----------------
#define WS_PROJL  0                   // f16 100K*64 = 12,800,000
#define WS_PROJR  12800000            // f16 100K*64 = 12,800,000
#define WS_BUFH   25600000            // f16 100K*64 = 12,800,000
#define WS_DEGI   38400000            // int 100K
#define WS_OFFS   38800000            // int 100K
#define WS_CSR    39200000            // int 1M
#define WS_CURS   43200000            // int 100K
#define WS_BSUM   43600000            // int 196
#define WS_BOFF   43604096            // int 196

extern "C" void kernel_launch(void* const* d_in, const int* in_sizes, int n_in,
                              void* d_out, int out_size, void* d_ws, size_t ws_size,
                              hipStream_t stream) {
    const float* x   = (const float*)d_in[0];
    const int*   ei  = (const int*)d_in[1];
    const float* ea  = (const float*)d_in[2];
    const float* Wl0 = (const float*)d_in[3];
    const float* bl0 = (const float*)d_in[4];
    const float* Wr0 = (const float*)d_in[5];
    const float* g0  = (const float*)d_in[6];
    const float* be0 = (const float*)d_in[7];
    const float* Wl1 = (const float*)d_in[8];
    const float* bl1 = (const float*)d_in[9];
    const float* Wr1 = (const float*)d_in[10];
    const float* g1  = (const float*)d_in[11];
    const float* be1 = (const float*)d_in[12];
    const float* W1  = (const float*)d_in[13];
    const float* b1  = (const float*)d_in[14];
    const float* W2  = (const float*)d_in[15];
    const float* b2  = (const float*)d_in[16];
    const float* W3  = (const float*)d_in[17];
    const float* b3  = (const float*)d_in[18];
    float* out = (float*)d_out;

    const int* src  = ei;
    const int* dstp = ei + NE;

    char* ws = (char*)d_ws;
    _Float16* projL = (_Float16*)(ws + WS_PROJL);
    _Float16* projR = (_Float16*)(ws + WS_PROJR);
    _Float16* bufH  = (_Float16*)(ws + WS_BUFH);
    int* degi   = (int*)(ws + WS_DEGI);
    int* offs   = (int*)(ws + WS_OFFS);
    int* csr    = (int*)(ws + WS_CSR);
    int* cursor = (int*)(ws + WS_CURS);
    int* bsum   = (int*)(ws + WS_BSUM);
    int* boff   = (int*)(ws + WS_BOFF);

    hipMemsetAsync(degi, 0, 400000, stream);
    deg_int_kernel<<<(NE + 255) / 256, 256, 0, stream>>>(dstp, degi);
    scan_partial<<<196, 256, 0, stream>>>(degi, bsum);
    scan_spine<<<1, 256, 0, stream>>>(bsum, boff);
    scan_final<<<196, 512, 0, stream>>>(degi, boff, offs, cursor);
    csr_fill<<<(NE + 255) / 256, 256, 0, stream>>>(src, dstp, cursor, csr);

    const int gemm_grid = (NN + 63) / 64;   // 1563
    // ---- layer 0 ----
    gemm_node<128, false><<<gemm_grid, 256, 0, stream>>>(x, Wl0, Wr0, projL, projR);
    gather_ln<<<NN / 4, 256, 0, stream>>>(projL, projR, csr, offs, degi, bl0, g0, be0, bufH);

    // ---- layer 1 ----
    gemm_node<64, true><<<gemm_grid, 256, 0, stream>>>(bufH, Wl1, Wr1, projL, projR);
    gather_ln<<<NN / 4, 256, 0, stream>>>(projL, projR, csr, offs, degi, bl1, g1, be1, bufH);

    // ---- edge MLP ----
    edge_mlp_mfma<<<3125, 256, 0, stream>>>(bufH, src, dstp, ea,
                                            W1, b1, W2, b2, W3, b3, out);
}